// Round 5
// baseline (163.120 us; speedup 1.0000x reference)
//
#include <hip/hip_runtime.h>
#include <hip/hip_bf16.h>

typedef __attribute__((ext_vector_type(8))) short short8;
typedef __attribute__((ext_vector_type(4))) float f32x4;

#define B_SZ 32
#define T_SZ 4096
#define H_SZ 512
#define NROWS (B_SZ * T_SZ)   // 131072

// packed fp32x2 -> bf16x2 (RNE), single v_cvt_pk_bf16_f32: a->low16, b->high16
static __device__ __forceinline__ unsigned int pack2(float a, float b) {
  unsigned int r;
  asm("v_cvt_pk_bf16_f32 %0, %1, %2" : "=v"(r) : "v"(a), "v"(b));
  return r;
}

// branch-free tanh, exact saturation at +/-inf: 1 - 2/(e^{2x}+1)
static __device__ __forceinline__ float fast_tanh(float x) {
  float e = __expf(2.0f * x);
  return 1.0f - 2.0f / (e + 1.0f);
}

// ---- W fp32 (512x512) -> bf16 in MFMA-fragment order ----
// fragment s = grow*64 + kt*4 + kslot; holds W[grow][kt*32 + kslot*8 .. +8]
// dst uint4 index = nb*1024 + kt*64 + (kslot*16 + g); a 16-g chunk = 16 KB contiguous
__global__ __launch_bounds__(256) void prep_w_kernel(
    const float* __restrict__ W, uint4* __restrict__ Wfrag) {
  int s = blockIdx.x * 256 + threadIdx.x;   // 0..32767
  int grow  = s >> 6;
  int kt    = (s >> 2) & 15;
  int kslot = s & 3;
  const float4* Wf4 = reinterpret_cast<const float4*>(W);
  float4 lo = Wf4[grow * 128 + kt * 8 + kslot * 2];
  float4 hi = Wf4[grow * 128 + kt * 8 + kslot * 2 + 1];
  uint4 u;
  u.x = pack2(lo.x, lo.y); u.y = pack2(lo.z, lo.w);
  u.z = pack2(hi.x, hi.y); u.w = pack2(hi.z, hi.w);
  int nb = grow >> 4, g = grow & 15;
  Wfrag[nb * 1024 + kt * 64 + kslot * 16 + g] = u;
}

// ---- scores[row] = sum_g v[g] * tanh( X[row,:] . W[g,:] ) ----
// 4 waves, wave owns 32 rows -> block M=128, grid 1024. A in regs full-K.
// B: 16-g chunks, TRIPLE-buffered 3x16 KB LDS, counted vmcnt(4) + raw s_barrier
// (never drains the in-flight prefetch — T3/T4 minimum recipe).
__global__ __launch_bounds__(256, 2) void score_kernel(
    const float* __restrict__ X, const uint4* __restrict__ Wfrag,
    const float* __restrict__ v, float* __restrict__ scores) {
  __shared__ unsigned char WsB[3][16384];

  const int tid   = threadIdx.x;
  const int lane  = tid & 63;
  const int wave  = tid >> 6;
  const int frow  = lane & 15;   // A: m row / B: g col
  const int kslot = lane >> 4;
  const size_t rowbase = (size_t)blockIdx.x * 128;

  // stage chunk c into buffer c%3: 16 KB linear, 4 KB (4 loads) per wave
  #define STAGE(c)                                                              \
    {                                                                           \
      const char* src = (const char*)Wfrag + (size_t)(c) * 16384 +              \
                        wave * 4096 + lane * 16;                                \
      unsigned char* dst = &WsB[(c) % 3][wave * 4096];                          \
      _Pragma("unroll")                                                         \
      for (int i = 0; i < 4; ++i)                                               \
        __builtin_amdgcn_global_load_lds((const unsigned int*)(src + i * 1024), \
                                         (unsigned int*)(dst + i * 1024), 16, 0, 0); \
    }

  // prologue: chunks 0,1 in flight; their latency hides under A-load/convert
  STAGE(0);
  STAGE(1);

  // A fragments for 2 row-sets: X[arow][kt*32 + kslot*8 .. +8], bf16-packed
  short8 afrag0[16], afrag1[16];
  {
    const float4* xr0 = reinterpret_cast<const float4*>(X + (rowbase + wave * 32 + frow) * H_SZ);
    const float4* xr1 = reinterpret_cast<const float4*>(X + (rowbase + wave * 32 + 16 + frow) * H_SZ);
    #pragma unroll
    for (int kt = 0; kt < 16; ++kt) {
      float4 lo0 = xr0[kt * 8 + kslot * 2];
      float4 hi0 = xr0[kt * 8 + kslot * 2 + 1];
      union { uint4 u; short8 s; } c0;
      c0.u.x = pack2(lo0.x, lo0.y); c0.u.y = pack2(lo0.z, lo0.w);
      c0.u.z = pack2(hi0.x, hi0.y); c0.u.w = pack2(hi0.z, hi0.w);
      afrag0[kt] = c0.s;
      float4 lo1 = xr1[kt * 8 + kslot * 2];
      float4 hi1 = xr1[kt * 8 + kslot * 2 + 1];
      union { uint4 u; short8 s; } c1;
      c1.u.x = pack2(lo1.x, lo1.y); c1.u.y = pack2(lo1.z, lo1.w);
      c1.u.z = pack2(hi1.x, hi1.y); c1.u.w = pack2(hi1.z, hi1.w);
      afrag1[kt] = c1.s;
    }
  }
  // prologue drain: A consumed, chunks 0,1 landed; all waves aligned once
  asm volatile("s_waitcnt vmcnt(0)" ::: "memory");
  __builtin_amdgcn_s_barrier();
  __builtin_amdgcn_sched_barrier(0);

  float red0[4] = {0.f, 0.f, 0.f, 0.f};
  float red1[4] = {0.f, 0.f, 0.f, 0.f};

  for (int ch = 0; ch < 32; ++ch) {
    // vmem issue order matters: vg first (its epilogue wait FIFO-drains only
    // older loads), then the prefetch for chunk ch+2
    float vg = v[ch * 16 + frow];
    if (ch + 2 < 32) STAGE(ch + 2);

    // 4 independent accumulator chains: [rowset][kt-parity]
    f32x4 acc[2][2];
    #pragma unroll
    for (int a = 0; a < 2; ++a)
      #pragma unroll
      for (int p = 0; p < 2; ++p)
        acc[a][p] = (f32x4){0.f, 0.f, 0.f, 0.f};

    const unsigned char* bb = &WsB[ch % 3][lane * 16];
    __builtin_amdgcn_s_setprio(1);
    #pragma unroll
    for (int kt = 0; kt < 16; ++kt) {
      short8 b = *reinterpret_cast<const short8*>(bb + kt * 1024);  // linear, conflict-free
      const int p = kt & 1;
      acc[0][p] = __builtin_amdgcn_mfma_f32_16x16x32_bf16(afrag0[kt], b, acc[0][p], 0, 0, 0);
      acc[1][p] = __builtin_amdgcn_mfma_f32_16x16x32_bf16(afrag1[kt], b, acc[1][p], 0, 0, 0);
    }
    __builtin_amdgcn_s_setprio(0);

    // D[m][n]: n = frow (g), m = kslot*4 + reg
    #pragma unroll
    for (int r = 0; r < 4; ++r) {
      red0[r] = fmaf(vg, fast_tanh(acc[0][0][r] + acc[0][1][r]), red0[r]);
      red1[r] = fmaf(vg, fast_tanh(acc[1][0][r] + acc[1][1][r]), red1[r]);
    }

    // counted-vmcnt barrier: chunk ch+1's 4 loads (older) complete; chunk
    // ch+2's 4 loads stay in flight across the barrier. Never vmcnt(0).
    if (ch < 31) {
      if (ch < 30) {
        asm volatile("s_waitcnt vmcnt(4)" ::: "memory");
      } else {
        asm volatile("s_waitcnt vmcnt(0)" ::: "memory");   // last prefetch: drain
      }
      __builtin_amdgcn_s_barrier();
      __builtin_amdgcn_sched_barrier(0);
    }
  }
  #undef STAGE

  // reduce over the 16 g-lanes (frow) within each kslot group
  #pragma unroll
  for (int r = 0; r < 4; ++r) {
    #pragma unroll
    for (int d = 1; d < 16; d <<= 1) {
      red0[r] += __shfl_xor(red0[r], d);
      red1[r] += __shfl_xor(red1[r], d);
    }
  }
  if (frow == 0) {
    float* sp = scores + rowbase + wave * 32 + kslot * 4;
    sp[0]  = red0[0]; sp[1]  = red0[1]; sp[2]  = red0[2]; sp[3]  = red0[3];
    sp[16] = red1[0]; sp[17] = red1[1]; sp[18] = red1[2]; sp[19] = red1[3];
  }
}

// ---- per-b softmax stats; rewrites scores in place with unnormalized exp ----
__global__ __launch_bounds__(256) void softmax_kernel(
    float* __restrict__ scores, float* __restrict__ denom) {
  const int b = blockIdx.x;
  float* s = scores + b * T_SZ;
  const int tid = threadIdx.x;
  __shared__ float redm[4], reds[4];

  float m = -1e30f;
  for (int t = tid; t < T_SZ; t += 256) m = fmaxf(m, s[t]);
  #pragma unroll
  for (int d = 1; d < 64; d <<= 1) m = fmaxf(m, __shfl_xor(m, d));
  if ((tid & 63) == 0) redm[tid >> 6] = m;
  __syncthreads();
  m = fmaxf(fmaxf(redm[0], redm[1]), fmaxf(redm[2], redm[3]));

  float sum = 0.f;
  for (int t = tid; t < T_SZ; t += 256) {
    float u = __expf(s[t] - m);
    s[t] = u;
    sum += u;
  }
  #pragma unroll
  for (int d = 1; d < 64; d <<= 1) sum += __shfl_xor(sum, d);
  if ((tid & 63) == 0) reds[tid >> 6] = sum;
  __syncthreads();
  if (tid == 0) denom[b] = reds[0] + reds[1] + reds[2] + reds[3];
}

// ---- partial[b][ch][h] = sum_{t in chunk} u_t * x[b,t,h] ----
__global__ __launch_bounds__(256) void wsum_kernel(
    const float* __restrict__ X, const float* __restrict__ u,
    float* __restrict__ partial) {
  const int ch = blockIdx.x;   // 32 chunks of 128 t
  const int b  = blockIdx.y;   // 32
  const float* xb = X + ((size_t)b * T_SZ + ch * 128) * H_SZ;
  const float* ub = u + b * T_SZ + ch * 128;
  const int h2 = threadIdx.x;  // float2 index
  float ax = 0.f, ay = 0.f;
  for (int tt = 0; tt < 128; ++tt) {
    float w = ub[tt];
    float2 xv = reinterpret_cast<const float2*>(xb + (size_t)tt * H_SZ)[h2];
    ax = fmaf(w, xv.x, ax);
    ay = fmaf(w, xv.y, ay);
  }
  float2 r; r.x = ax; r.y = ay;
  reinterpret_cast<float2*>(partial + ((size_t)b * 32 + ch) * H_SZ)[h2] = r;
}

// ---- out[b][h] = (1/denom_b) * sum_ch partial[b][ch][h] ----
__global__ __launch_bounds__(256) void finalize_kernel(
    const float* __restrict__ partial, const float* __restrict__ denom,
    float* __restrict__ out) {
  const int b = blockIdx.x;
  const float inv = 1.0f / denom[b];
  for (int h = threadIdx.x; h < H_SZ; h += 256) {
    float s = 0.f;
    #pragma unroll
    for (int c = 0; c < 32; ++c) s += partial[((size_t)b * 32 + c) * H_SZ + h];
    out[b * H_SZ + h] = s * inv;
  }
}

extern "C" void kernel_launch(void* const* d_in, const int* in_sizes, int n_in,
                              void* d_out, int out_size, void* d_ws, size_t ws_size,
                              hipStream_t stream) {
  const float* X = (const float*)d_in[0];   // (32,4096,512)
  const float* W = (const float*)d_in[1];   // (512,512)
  const float* v = (const float*)d_in[2];   // (512,)
  float* out = (float*)d_out;               // (32,512) fp32
  unsigned char* ws = (unsigned char*)d_ws;

  uint4* Wfrag   = (uint4*)(ws);                        // 512 KB
  float* scores  = (float*)(ws + (512u << 10));         // 512 KB (becomes u)
  float* denom   = (float*)(ws + (1024u << 10));        // 128 B
  float* partial = (float*)(ws + (1024u << 10) + 512);  // 2 MB

  prep_w_kernel<<<128, 256, 0, stream>>>(W, Wfrag);
  score_kernel<<<NROWS / 128, 256, 0, stream>>>(X, Wfrag, v, scores);
  softmax_kernel<<<B_SZ, 256, 0, stream>>>(scores, denom);
  dim3 g(32, B_SZ);
  wsum_kernel<<<g, 256, 0, stream>>>(X, scores, partial);
  finalize_kernel<<<B_SZ, 256, 0, stream>>>(partial, denom, out);
}